// Round 6
// baseline (672.811 us; speedup 1.0000x reference)
//
#include <hip/hip_runtime.h>
#include <hip/hip_bf16.h>
#include <hip/hip_cooperative_groups.h>
#include <stdint.h>

namespace cg = cooperative_groups;

#define TOKENS 512
#define HDIM   2048
#define IDIM   1408
#define SIDIM  5632
#define NEXP   60
#define TOPK   4
#define NSLOTS (TOKENS*TOPK)   /* 2048 */
#define ROWPAD 64

#define NQ_G 253   /* per-XCD gate/up items: 88 shared + 165 expert (60*22/8) */
#define NQ_D 272   /* per-XCD down items: 32 shared + 240 expert (60*32/8)    */

// counted-vmcnt barrier primitives (T3/T4): raw s_barrier, NO vmcnt(0) drain
#define VMWAIT(N) asm volatile("s_waitcnt vmcnt(" #N ")" ::: "memory")
#define SBAR()    asm volatile("s_barrier" ::: "memory")

typedef __attribute__((ext_vector_type(8))) short bf16x8;
typedef __attribute__((ext_vector_type(4))) float f32x4;

__device__ __forceinline__ short f2bf(float f){
  uint32_t u = __float_as_uint(f);
  u = (u + 0x7fffu + ((u >> 16) & 1u)) >> 16;   // RNE
  return (short)(u & 0xffffu);
}

__device__ __forceinline__ bf16x8 pack8(float4 a, float4 b){
  bf16x8 r;
  r[0]=f2bf(a.x); r[1]=f2bf(a.y); r[2]=f2bf(a.z); r[3]=f2bf(a.w);
  r[4]=f2bf(b.x); r[5]=f2bf(b.y); r[6]=f2bf(b.z); r[7]=f2bf(b.w);
  return r;
}

__device__ __forceinline__ bf16x8 as_bf16x8(float4 v){
  union { float4 f; bf16x8 b; } u; u.f = v; return u.b;
}

__device__ __forceinline__ f32x4 zero4(){
  f32x4 z; z[0]=0.f; z[1]=0.f; z[2]=0.f; z[3]=0.f; return z;
}

__device__ __forceinline__ f32x4 mfma16(bf16x8 a, bf16x8 b, f32x4 c){
  return __builtin_amdgcn_mfma_f32_16x16x32_bf16(a, b, c, 0, 0, 0);
}

// ================== K-step-32 staged tiles (rule #21 both-sides swizzle) =====
// W tile: 64 rows x 32 fp32 = 8 KB = [64][8] float4 units, rotated by row&7.
// LDS dest linear (HW requirement); permutation rides on per-lane GLOBAL src.
__device__ __forceinline__ void stage_w32(float4* tile, const float* __restrict__ W,
                                          int K, int k0, int tid){
  int l = tid & 63, wv = tid >> 6;
  #pragma unroll
  for (int j=0;j<2;j++){
    int u0 = j*256 + wv*64;                 // wave-uniform
    int u  = u0 + l;
    int row = u >> 3;
    int lu  = ((u & 7) - (row & 7)) & 7;
    const float* src = W + (size_t)row*K + k0 + lu*4;
    __builtin_amdgcn_global_load_lds(
        (const __attribute__((address_space(1))) void*)src,
        (__attribute__((address_space(3))) void*)(tile + u0), 16, 0, 0);
  }
}

__device__ __forceinline__ bf16x8 read_wfrag32(const float4* tile, int r, int kq){
  int rot = r & 7;
  const float4* row = tile + (size_t)r*8;
  float4 f0 = row[(2*kq     + rot) & 7];
  float4 f1 = row[(2*kq + 1 + rot) & 7];
  return pack8(f0, f1);
}

// A tile: 64 rows x 32 bf16 = 4 KB = [64][4] float4 units, rotated by row&3.
__device__ __forceinline__ void stage_a32(float4* tile, const short* __restrict__ Arows,
                                          int K, int k0, int tid){
  int l = tid & 63, wv = tid >> 6;
  int u0 = wv*64;
  int u  = u0 + l;
  int row = u >> 2;
  int lu  = ((u & 3) - (row & 3)) & 3;
  const short* src = Arows + (size_t)row*K + k0 + lu*8;
  __builtin_amdgcn_global_load_lds(
      (const __attribute__((address_space(1))) void*)src,
      (__attribute__((address_space(3))) void*)(tile + u0), 16, 0, 0);
}

__device__ __forceinline__ void read_afrag32(const float4* tile, int c16, int kq,
                                             bf16x8* av){
  #pragma unroll
  for (int mf=0; mf<4; mf++){
    int row = c16 + 16*mf;
    av[mf] = as_bf16x8(tile[(size_t)row*4 + ((kq + row) & 3)]);
  }
}

// ======================= mega-kernel argument block ==========================
struct MegaArgs {
  const float *x, *rw, *gw, *uw, *dw, *sgw, *suw, *sdw, *egw;
  int *counts, *fill, *offsets, *topk_idx, *slot_of, *qg, *qd, *mb;
  float *topk_w, *gates, *dslot, *shdown, *out;
  short *xb, *xg, *act, *shact;
};

// ---------------- phase bodies (device functions) ----------------------------
__device__ __forceinline__ void router_body(const MegaArgs& a, int t, int lane){
  const float* xr = a.x + (size_t)t*HDIM;
  float xv[HDIM/64];
  #pragma unroll
  for (int i=0;i<HDIM/64;i++) xv[i] = xr[lane + 64*i];

  float mylogit = -1e30f;
  for (int e=0;e<NEXP;e++){
    const float* w = a.rw + (size_t)e*HDIM;
    float acc = 0.f;
    #pragma unroll
    for (int i=0;i<HDIM/64;i++) acc += xv[i]*w[lane+64*i];
    #pragma unroll
    for (int s=32;s>0;s>>=1) acc += __shfl_xor(acc, s);
    if (lane == e) mylogit = acc;
  }
  {
    float acc = 0.f;
    #pragma unroll
    for (int i=0;i<HDIM/64;i++) acc += xv[i]*a.egw[lane+64*i];
    #pragma unroll
    for (int s=32;s>0;s>>=1) acc += __shfl_xor(acc, s);
    if (lane == 0) a.gates[t] = 1.f/(1.f + __expf(-acc));
  }
  float m = mylogit;
  #pragma unroll
  for (int s=32;s>0;s>>=1) m = fmaxf(m, __shfl_xor(m, s));
  float p = (lane < NEXP) ? __expf(mylogit - m) : 0.f;
  float sum = p;
  #pragma unroll
  for (int s=32;s>0;s>>=1) sum += __shfl_xor(sum, s);
  float prob = p / sum;
  for (int k=0;k<TOPK;k++){
    float v = prob; int idx = lane;
    #pragma unroll
    for (int s=32;s>0;s>>=1){
      float ov = __shfl_xor(v, s); int oi = __shfl_xor(idx, s);
      if (ov > v || (ov == v && oi < idx)){ v = ov; idx = oi; }
    }
    if (lane == 0){
      a.topk_idx[t*TOPK+k] = idx;
      a.topk_w[t*TOPK+k]  = v;
      atomicAdd(&a.counts[idx], 1);
    }
    if (lane == idx) prob = -1e30f;
  }
}

__device__ __forceinline__ void scatter_body(const MegaArgs& a, int t, int tid, int bid){
  if (tid == 0){
    int e0 = a.topk_idx[t*TOPK+0], e1 = a.topk_idx[t*TOPK+1];
    int e2 = a.topk_idx[t*TOPK+2], e3 = a.topk_idx[t*TOPK+3];
    int o0=0,o1=0,o2=0,o3=0, acc=0;
    for (int e=0;e<NEXP;e++){
      int c = a.counts[e];
      if (bid == 0) a.offsets[e] = acc;         // block 0 publishes prefix
      if (e==e0) o0=acc; if (e==e1) o1=acc;
      if (e==e2) o2=acc; if (e==e3) o3=acc;
      acc += c;
    }
    if (bid == 0) a.offsets[NEXP] = acc;
    int s0 = o0 + atomicAdd(&a.fill[e0],1);
    int s1 = o1 + atomicAdd(&a.fill[e1],1);
    int s2 = o2 + atomicAdd(&a.fill[e2],1);
    int s3 = o3 + atomicAdd(&a.fill[e3],1);
    a.slot_of[t*TOPK+0]=s0; a.slot_of[t*TOPK+1]=s1;
    a.slot_of[t*TOPK+2]=s2; a.slot_of[t*TOPK+3]=s3;
  }
  __syncthreads();                               // barrier => slot_of visible
  int4 sl = ((const int4*)a.slot_of)[t];
  const float4* xr = (const float4*)(a.x + (size_t)t*HDIM);
  float4 v0 = xr[tid*2], v1 = xr[tid*2+1];
  bf16x8 b = pack8(v0, v1);
  *(bf16x8*)(a.xb + (size_t)t*HDIM + tid*8) = b;
  *(bf16x8*)(a.xg + (size_t)sl.x*HDIM + tid*8) = b;
  *(bf16x8*)(a.xg + (size_t)sl.y*HDIM + tid*8) = b;
  *(bf16x8*)(a.xg + (size_t)sl.z*HDIM + tid*8) = b;
  *(bf16x8*)(a.xg + (size_t)sl.w*HDIM + tid*8) = b;
}

// gate+up GEMM item. LDS: G0,G1,U0,U1 (8KB) + A0,A1 (4KB) = 40 KB.
__device__ __forceinline__ void gateup_item(const MegaArgs& a, char* smem,
                                            int q, int pos, int tid){
  float4* G0 = (float4*)smem;
  float4* G1 = G0 + 512;
  float4* U0 = G1 + 512;
  float4* U1 = U0 + 512;
  float4* A0 = U1 + 512;
  float4* A1 = A0 + 256;

  const float *Wg, *Wu; const short* Abase; short* outp;
  int NI, bx, m_start, m_end;
  if (pos < 88){                        // shared expert (m-tile = q)
    bx = pos;
    Wg = a.sgw; Wu = a.suw; Abase = a.xb; outp = a.shact;
    NI = SIDIM; m_start = q*64; m_end = m_start + 64;
  } else {                              // routed experts, same-expert contiguous in q
    int qq = q*165 + (pos - 88);
    int e = qq/22; bx = qq - e*22;
    size_t wo = (size_t)e * IDIM * HDIM;
    Wg = a.gw + wo; Wu = a.uw + wo;
    Abase = a.xg; outp = a.act;
    NI = IDIM; m_start = a.offsets[e]; m_end = a.offsets[e+1];
  }
  if (m_start >= m_end) return;
  const int K = HDIM;

  int lane = tid & 63;
  int wv   = tid >> 6;
  int c16 = lane & 15, kq = lane >> 4;
  int wrow = bx*64 + wv*16 + c16;
  int r    = wv*16 + c16;
  const float* WgT = Wg + (size_t)(bx*64)*K;
  const float* WuT = Wu + (size_t)(bx*64)*K;

  for (int m0 = m_start; m0 < m_end; m0 += 64){
    int mrem = m_end - m0;
    const short* Ar = Abase + (size_t)m0*K;
    f32x4 accg[4], accu[4];
    #pragma unroll
    for (int i=0;i<4;i++){ accg[i] = zero4(); accu[i] = zero4(); }

    stage_w32(G0, WgT, K, 0, tid);
    stage_w32(U0, WuT, K, 0, tid);
    stage_a32(A0, Ar,  K, 0, tid);

    for (int k0 = 0; k0 < K; k0 += 64){
      stage_w32(G1, WgT, K, k0+32, tid);
      stage_w32(U1, WuT, K, k0+32, tid);
      stage_a32(A1, Ar,  K, k0+32, tid);
      VMWAIT(5); SBAR();
      {
        bf16x8 av[4];
        read_afrag32(A0, c16, kq, av);
        bf16x8 bg = read_wfrag32(G0, r, kq);
        bf16x8 bu = read_wfrag32(U0, r, kq);
        #pragma unroll
        for (int mf=0; mf<4; mf++){
          accg[mf] = mfma16(av[mf], bg, accg[mf]);
          accu[mf] = mfma16(av[mf], bu, accu[mf]);
        }
      }
      SBAR();
      if (k0 + 64 < K){
        stage_w32(G0, WgT, K, k0+64, tid);
        stage_w32(U0, WuT, K, k0+64, tid);
        stage_a32(A0, Ar,  K, k0+64, tid);
        VMWAIT(5);
      } else {
        VMWAIT(0);
      }
      SBAR();
      {
        bf16x8 av[4];
        read_afrag32(A1, c16, kq, av);
        bf16x8 bg = read_wfrag32(G1, r, kq);
        bf16x8 bu = read_wfrag32(U1, r, kq);
        #pragma unroll
        for (int mf=0; mf<4; mf++){
          accg[mf] = mfma16(av[mf], bg, accg[mf]);
          accu[mf] = mfma16(av[mf], bu, accu[mf]);
        }
      }
      SBAR();
    }

    #pragma unroll
    for (int mf=0; mf<4; mf++){
      #pragma unroll
      for (int j=0;j<4;j++){
        int mrow = mf*16 + kq*4 + j;
        if (mrow < mrem){
          float g = accg[mf][j], u = accu[mf][j];
          float s = g * u / (1.f + __expf(-g));
          outp[(size_t)(m0+mrow)*NI + wrow] = f2bf(s);
        }
      }
    }
  }
}

// down GEMM item. LDS: W0,W1 (8KB) + A0,A1 (4KB) = 24 KB (subset of 40).
__device__ __forceinline__ void down_item(const MegaArgs& a, char* smem,
                                          int q, int pos, int tid){
  float4* W0 = (float4*)smem;
  float4* W1 = W0 + 512;
  float4* A0 = W1 + 512;
  float4* A1 = A0 + 256;

  const float* W; const short* Abase; float* outp;
  int K, bx, m_start, m_end;
  if (pos < 32){                        // shared (K=5632, longest: queued first)
    bx = pos;
    W = a.sdw; Abase = a.shact; outp = a.shdown; K = SIDIM;
    m_start = q*64; m_end = m_start + 64;
  } else {
    int qq = q*240 + (pos - 32);
    int e = qq >> 5; bx = qq & 31;
    W = a.dw + (size_t)e * HDIM * IDIM;
    Abase = a.act; outp = a.dslot; K = IDIM;
    m_start = a.offsets[e]; m_end = a.offsets[e+1];
  }
  if (m_start >= m_end) return;

  int lane = tid & 63;
  int wv   = tid >> 6;
  int c16 = lane & 15, kq = lane >> 4;
  int wrow = bx*64 + wv*16 + c16;
  int r    = wv*16 + c16;
  const float* WT = W + (size_t)(bx*64)*K;

  for (int m0 = m_start; m0 < m_end; m0 += 64){
    int mrem = m_end - m0;
    const short* Ar = Abase + (size_t)m0*K;
    f32x4 acc[4];
    #pragma unroll
    for (int i=0;i<4;i++) acc[i] = zero4();

    stage_w32(W0, WT, K, 0, tid);
    stage_a32(A0, Ar, K, 0, tid);

    for (int k0 = 0; k0 < K; k0 += 64){
      stage_w32(W1, WT, K, k0+32, tid);
      stage_a32(A1, Ar, K, k0+32, tid);
      VMWAIT(3); SBAR();
      {
        bf16x8 av[4];
        read_afrag32(A0, c16, kq, av);
        bf16x8 b = read_wfrag32(W0, r, kq);
        #pragma unroll
        for (int mf=0; mf<4; mf++)
          acc[mf] = mfma16(av[mf], b, acc[mf]);
      }
      SBAR();
      if (k0 + 64 < K){
        stage_w32(W0, WT, K, k0+64, tid);
        stage_a32(A0, Ar, K, k0+64, tid);
        VMWAIT(3);
      } else {
        VMWAIT(0);
      }
      SBAR();
      {
        bf16x8 av[4];
        read_afrag32(A1, c16, kq, av);
        bf16x8 b = read_wfrag32(W1, r, kq);
        #pragma unroll
        for (int mf=0; mf<4; mf++)
          acc[mf] = mfma16(av[mf], b, acc[mf]);
      }
      SBAR();
    }

    #pragma unroll
    for (int mf=0; mf<4; mf++){
      #pragma unroll
      for (int j=0;j<4;j++){
        int mrow = mf*16 + kq*4 + j;
        if (mrow < mrem)
          outp[(size_t)(m0+mrow)*HDIM + wrow] = acc[mf][j];
      }
    }
  }
}

__device__ __forceinline__ void combine_body(const MegaArgs& a, int t, int tid){
  int4  sl = ((const int4*)a.slot_of)[t];
  float4 w = ((const float4*)a.topk_w)[t];
  float sg = a.gates[t];
  const float* r0 = a.dslot + (size_t)sl.x*HDIM;
  const float* r1 = a.dslot + (size_t)sl.y*HDIM;
  const float* r2 = a.dslot + (size_t)sl.z*HDIM;
  const float* r3 = a.dslot + (size_t)sl.w*HDIM;
  const float* rs = a.shdown + (size_t)t*HDIM;
  float* o = a.out + (size_t)t*HDIM;
  #pragma unroll
  for (int it=0; it<HDIM/(256*4); ++it){
    int h = (tid + it*256) * 4;
    float4 a0 = *(const float4*)(r0+h);
    float4 a1 = *(const float4*)(r1+h);
    float4 a2 = *(const float4*)(r2+h);
    float4 a3 = *(const float4*)(r3+h);
    float4 as = *(const float4*)(rs+h);
    float4 r;
    r.x = w.x*a0.x + w.y*a1.x + w.z*a2.x + w.w*a3.x + sg*as.x;
    r.y = w.x*a0.y + w.y*a1.y + w.z*a2.y + w.w*a3.y + sg*as.y;
    r.z = w.x*a0.z + w.y*a1.z + w.z*a2.z + w.w*a3.z + sg*as.z;
    r.w = w.x*a0.w + w.y*a1.w + w.z*a2.w + w.w*a3.w + sg*as.w;
    *(float4*)(o+h) = r;
  }
}

// ======================= the cooperative mega-kernel =========================
__global__ __launch_bounds__(256, 4) void mega(MegaArgs a)
{
  extern __shared__ __align__(16) char smem[];
  cg::grid_group grid = cg::this_grid();
  int bid = blockIdx.x, tid = threadIdx.x;
  int wv = tid >> 6, lane = tid & 63;

  // phase R: router — 1 wave per token, blocks 0..127
  if (bid < 128) router_body(a, bid*4 + wv, lane);
  __threadfence(); grid.sync();

  // phase S: scatter (+ block0 publishes prefix offsets)
  if (bid < TOKENS) scatter_body(a, bid, tid, bid);
  __threadfence(); grid.sync();

  // phase G: gate+up, per-XCD work queues with stealing
  {
    int myq = bid & 7;
    for (int dq=0; dq<8; ++dq){
      int q = (myq + dq) & 7;
      while (true){
        if (tid == 0) a.mb[bid] = atomicAdd(&a.qg[q], 1);
        __syncthreads();
        int pos = a.mb[bid];
        if (pos >= NQ_G) break;
        gateup_item(a, smem, q, pos, tid);
        __syncthreads();
      }
    }
  }
  __threadfence(); grid.sync();

  // phase D: down, per-XCD work queues with stealing
  {
    int myq = bid & 7;
    for (int dq=0; dq<8; ++dq){
      int q = (myq + dq) & 7;
      while (true){
        if (tid == 0) a.mb[bid] = atomicAdd(&a.qd[q], 1);
        __syncthreads();
        int pos = a.mb[bid];
        if (pos >= NQ_D) break;
        down_item(a, smem, q, pos, tid);
        __syncthreads();
      }
    }
  }
  __threadfence(); grid.sync();

  // phase C: combine
  if (bid < TOKENS) combine_body(a, bid, tid);
}

// ======================= fallback multi-kernel path ==========================
__global__ __launch_bounds__(64) void router_kernel(
    const float* __restrict__ x, const float* __restrict__ rw,
    const float* __restrict__ egw, int* __restrict__ topk_idx,
    float* __restrict__ topk_w, float* __restrict__ gates,
    int* __restrict__ counts)
{
  MegaArgs a{}; a.x=x; a.rw=rw; a.egw=egw; a.topk_idx=topk_idx;
  a.topk_w=topk_w; a.gates=gates; a.counts=counts;
  router_body(a, blockIdx.x, threadIdx.x);
}

__global__ void prefix_kernel(const int* __restrict__ counts, int* __restrict__ offsets)
{
  if (threadIdx.x == 0){
    int acc = 0;
    for (int e=0;e<NEXP;e++){ offsets[e] = acc; acc += counts[e]; }
    offsets[NEXP] = acc;
  }
}

__global__ __launch_bounds__(256) void scatter_kernel(
    const float* __restrict__ x, const int* __restrict__ topk_idx,
    const int* __restrict__ offsets, int* __restrict__ fill,
    int* __restrict__ slot_of, __hip_bfloat16* __restrict__ xg,
    __hip_bfloat16* __restrict__ xb)
{
  int t = blockIdx.x, tid = threadIdx.x;
  __shared__ int sl[TOPK];
  if (tid == 0){
    for (int k=0;k<TOPK;k++){
      int e = topk_idx[t*TOPK+k];
      int pos = atomicAdd(&fill[e], 1);
      int s = offsets[e] + pos;
      slot_of[t*TOPK+k] = s;
      sl[k] = s;
    }
  }
  __syncthreads();
  const float4* xr = (const float4*)(x + (size_t)t*HDIM);
  float4 v0 = xr[tid*2], v1 = xr[tid*2+1];
  bf16x8 b = pack8(v0, v1);
  *(bf16x8*)((short*)xb + (size_t)t*HDIM + tid*8) = b;
  #pragma unroll
  for (int k=0;k<TOPK;k++)
    *(bf16x8*)((short*)xg + (size_t)sl[k]*HDIM + tid*8) = b;
}

__global__ __launch_bounds__(256, 4) void gateup_all(MegaArgs a)
{
  extern __shared__ __align__(16) char smem[];
  int bid = blockIdx.x;
  gateup_item(a, smem, bid & 7, bid >> 3, threadIdx.x);
}

__global__ __launch_bounds__(256, 4) void down_all(MegaArgs a)
{
  extern __shared__ __align__(16) char smem[];
  int bid = blockIdx.x;
  down_item(a, smem, bid & 7, bid >> 3, threadIdx.x);
}

__global__ __launch_bounds__(256) void combine_kernel(MegaArgs a)
{
  combine_body(a, blockIdx.x, threadIdx.x);
}

// ======================= host launcher =======================================
extern "C" void kernel_launch(void* const* d_in, const int* in_sizes, int n_in,
                              void* d_out, int out_size, void* d_ws, size_t ws_size,
                              hipStream_t stream)
{
  MegaArgs a;
  a.x   = (const float*)d_in[0];
  a.rw  = (const float*)d_in[1];
  a.gw  = (const float*)d_in[2];
  a.uw  = (const float*)d_in[3];
  a.dw  = (const float*)d_in[4];
  a.sgw = (const float*)d_in[5];
  a.suw = (const float*)d_in[6];
  a.sdw = (const float*)d_in[7];
  a.egw = (const float*)d_in[8];
  a.out = (float*)d_out;

  char* p = (char*)d_ws;
  auto alloc = [&](size_t bytes)->char*{
    char* r = p; p += (bytes + 255) & ~(size_t)255; return r;
  };
  // contiguous zero-block: counts(60) fill(60) qg(8) qd(8)
  int* zblock   = (int*)alloc((NEXP+NEXP+8+8)*4);
  a.counts = zblock;
  a.fill   = zblock + NEXP;
  a.qg     = zblock + 2*NEXP;
  a.qd     = zblock + 2*NEXP + 8;
  a.offsets  = (int*)  alloc((NEXP+1)*4);
  a.topk_idx = (int*)  alloc(NSLOTS*4);
  a.topk_w   = (float*)alloc(NSLOTS*4);
  a.slot_of  = (int*)  alloc(NSLOTS*4);
  a.gates    = (float*)alloc(TOKENS*4);
  a.mb       = (int*)  alloc(1024*4);
  a.xb    = (short*)alloc((size_t)TOKENS*HDIM*2);
  a.xg    = (short*)alloc((size_t)(NSLOTS+ROWPAD)*HDIM*2);
  a.act   = (short*)alloc((size_t)(NSLOTS+ROWPAD)*IDIM*2);
  a.shact = (short*)alloc((size_t)TOKENS*SIDIM*2);
  a.dslot  = (float*)alloc((size_t)NSLOTS*HDIM*4);
  a.shdown = (float*)alloc((size_t)TOKENS*HDIM*4);
  if ((size_t)(p - (char*)d_ws) > ws_size) return;

  hipMemsetAsync(zblock, 0, (NEXP+NEXP+8+8)*4, stream);

  // cooperative mega-kernel if it fits fully resident; else multi-kernel
  int nb = 0;
  hipError_t qerr = hipOccupancyMaxActiveBlocksPerMultiprocessor(&nb, mega, 256, 40*1024);
  int gridsz = 0;
  if (qerr == hipSuccess){
    if (nb >= 4) gridsz = 1024;
    else if (nb == 3) gridsz = 768;
  }
  if (gridsz){
    void* kargs[] = { (void*)&a };
    hipError_t err = hipLaunchCooperativeKernel((const void*)mega, dim3(gridsz),
                                                dim3(256), kargs, 40*1024, stream);
    if (err == hipSuccess) return;
  }

  // -------- fallback: round-5 proven sequence --------
  router_kernel <<<TOKENS, 64, 0, stream>>>(a.x, a.rw, a.egw, a.topk_idx,
                                            a.topk_w, a.gates, a.counts);
  prefix_kernel <<<1, 64, 0, stream>>>(a.counts, a.offsets);
  scatter_kernel<<<TOKENS, 256, 0, stream>>>(a.x, a.topk_idx, a.offsets, a.fill,
                                             a.slot_of, (__hip_bfloat16*)a.xg,
                                             (__hip_bfloat16*)a.xb);
  gateup_all<<<8*NQ_G, 256, 40*1024, stream>>>(a);
  down_all  <<<8*NQ_D, 256, 24*1024, stream>>>(a);
  combine_kernel<<<TOKENS, 256, 0, stream>>>(a);
}